// Round 1
// baseline (213.938 us; speedup 1.0000x reference)
//
#include <hip/hip_runtime.h>
#include <math.h>

#define BB 2
#define CC 256
#define TT 16
#define HH 64
#define WW 64
#define NN 128
#define OT 2
#define OH 7
#define OW 7

// one thread per output element (n, c, ot, oh, ow); out layout N,C,OT,OH,OW
__global__ __launch_bounds__(256) void roipool3d_kernel(
    const float* __restrict__ feat,
    const float* __restrict__ rois,
    float* __restrict__ out,
    int total)
{
    int idx = blockIdx.x * blockDim.x + threadIdx.x;
    if (idx >= total) return;

    int ow = idx % OW;
    int oh = (idx / OW) % OH;
    int ot = (idx / (OW * OH)) % OT;
    int c  = (idx / (OW * OH * OT)) % CC;
    int n  = idx / (OW * OH * OT * CC);

    const float* r = rois + n * 7;
    int b  = (int)r[0];
    int t1 = (int)floorf(r[1]);
    int x1 = (int)floorf(r[2]);
    int y1 = (int)floorf(r[3]);
    int t2 = (int)floorf(r[4]);
    int x2 = (int)floorf(r[5]);
    int y2 = (int)floorf(r[6]);

    int lt = t2 - t1 + 1;
    int lh = y2 - y1 + 1;
    int lw = x2 - x1 + 1;

    int ts = (ot * lt) / OT;
    int te = ((ot + 1) * lt + OT - 1) / OT;
    int hs = (oh * lh) / OH;
    int he = ((oh + 1) * lh + OH - 1) / OH;
    int ws = (ow * lw) / OW;
    int we = ((ow + 1) * lw + OW - 1) / OW;

    const float* fbase = feat + ((size_t)b * CC + c) * (TT * HH * WW);

    float m = -INFINITY;
    for (int t = t1 + ts; t < t1 + te; ++t) {
        const float* ft = fbase + t * (HH * WW);
        for (int y = y1 + hs; y < y1 + he; ++y) {
            const float* fy = ft + y * WW;
            for (int x = x1 + ws; x < x1 + we; ++x) {
                m = fmaxf(m, fy[x]);
            }
        }
    }
    out[idx] = m;
}

extern "C" void kernel_launch(void* const* d_in, const int* in_sizes, int n_in,
                              void* d_out, int out_size, void* d_ws, size_t ws_size,
                              hipStream_t stream) {
    const float* feat = (const float*)d_in[0];
    const float* rois = (const float*)d_in[1];
    float* out = (float*)d_out;

    int total = NN * CC * OT * OH * OW;  // 3,211,264
    int block = 256;
    int grid = (total + block - 1) / block;
    roipool3d_kernel<<<grid, block, 0, stream>>>(feat, rois, out, total);
}

// Round 2
// 201.085 us; speedup vs baseline: 1.0639x; 1.0639x over previous
//
#include <hip/hip_runtime.h>
#include <math.h>

#define BB 2
#define CC 256
#define TT 16
#define HH 64
#define WW 64
#define NN 128
#define OT 2
#define OH 7
#define OW 7

#define NXCD 8
#define C_PER_XCD (CC / NXCD)            // 32
#define PLANE (NN * OT * OH * OW)        // 12544 outputs per channel
#define BLOCKS_PER_C (PLANE / 256)       // 49
#define BIN (OT * OH * OW)               // 98 outputs per (n,c)

// Grid = 8 XCDs * 32 channels * 49 blocks = 12544 blocks of 256.
// blockIdx % 8 selects XCD (HW round-robin heuristic); each XCD walks its
// 32 channels in sequence so the 524 KB per-channel feature slice stays
// L2-resident while all 128 ROIs consume it.
__global__ __launch_bounds__(256) void roipool3d_kernel(
    const float* __restrict__ feat,
    const float* __restrict__ rois,
    float* __restrict__ out)
{
    int wg   = blockIdx.x;
    int xcd  = wg % NXCD;
    int i    = wg / NXCD;                 // 0..1567 slot within XCD
    int c    = xcd * C_PER_XCD + i / BLOCKS_PER_C;
    int p    = (i % BLOCKS_PER_C) * 256 + threadIdx.x;  // 0..12543

    int n   = p / BIN;
    int rem = p % BIN;
    int ot  = rem / (OH * OW);
    int oh  = (rem / OW) % OH;
    int ow  = rem % OW;

    const float* r = rois + n * 7;
    int b  = (int)r[0];
    int t1 = (int)r[1];
    int x1 = (int)r[2];
    int y1 = (int)r[3];
    int t2 = (int)r[4];
    int x2 = (int)r[5];
    int y2 = (int)r[6];

    int lt = t2 - t1 + 1;
    int lh = y2 - y1 + 1;
    int lw = x2 - x1 + 1;

    int ts = (ot * lt) / OT;
    int te = ((ot + 1) * lt + OT - 1) / OT;
    int hs = (oh * lh) / OH;
    int he = ((oh + 1) * lh + OH - 1) / OH;
    int ws = (ow * lw) / OW;
    int we = ((ow + 1) * lw + OW - 1) / OW;

    const float* fbase = feat + ((size_t)b * CC + c) * (TT * HH * WW);

    float m = -INFINITY;
    for (int t = t1 + ts; t < t1 + te; ++t) {
        const float* ft = fbase + t * (HH * WW);
        for (int y = y1 + hs; y < y1 + he; ++y) {
            const float* fy = ft + y * WW;
            for (int x = x1 + ws; x < x1 + we; ++x) {
                m = fmaxf(m, fy[x]);
            }
        }
    }

    out[((size_t)n * CC + c) * BIN + rem] = m;
}

extern "C" void kernel_launch(void* const* d_in, const int* in_sizes, int n_in,
                              void* d_out, int out_size, void* d_ws, size_t ws_size,
                              hipStream_t stream) {
    const float* feat = (const float*)d_in[0];
    const float* rois = (const float*)d_in[1];
    float* out = (float*)d_out;

    int grid = NXCD * C_PER_XCD * BLOCKS_PER_C;  // 12544
    roipool3d_kernel<<<grid, 256, 0, stream>>>(feat, rois, out);
}